// Round 1
// baseline (441.876 us; speedup 1.0000x reference)
//
#include <hip/hip_runtime.h>
#include <math.h>

#define BDIM 8
#define TDIM 2048
#define EDIM 1024
#define HDIM 64

// ---------------------------------------------------------------------------
// QKV projection: Q = x@Wq + bq (and K, V).  x:[B*T, E], W:[E, H=64].
// Grid: (B*T)/64 = 256 blocks, 256 threads.  64 rows per block.
// LDS: x tile stored TRANSPOSED [e][row] so the compute loop does float4
// reads (wave-uniform address -> broadcast, no conflicts). W tiles [e][h],
// lanes read consecutive h -> conflict-free.
// ---------------------------------------------------------------------------
__global__ __launch_bounds__(256) void proj_kernel(
    const float* __restrict__ x,
    const float* __restrict__ Wq, const float* __restrict__ bq,
    const float* __restrict__ Wk, const float* __restrict__ bk,
    const float* __restrict__ Wv, const float* __restrict__ bv,
    float* __restrict__ Qb, float* __restrict__ Kb, float* __restrict__ Vb)
{
    __shared__ float xsT[64][68];    // [e][row], pad 68 (16B-aligned rows)
    __shared__ float wqs[64][64];    // [e][h]
    __shared__ float wks[64][64];
    __shared__ float wvs[64][64];

    const int t   = threadIdx.x;
    const int tx  = t & 63;          // h index (lane)
    const int wv_ = t >> 6;          // wave id 0..3 -> owns rows wv_*16 .. +15
    const int row0 = blockIdx.x * 64;

    float accq[16], acck[16], accv[16];
#pragma unroll
    for (int r = 0; r < 16; ++r) { accq[r] = 0.f; acck[r] = 0.f; accv[r] = 0.f; }

    for (int kt = 0; kt < EDIM / 64; ++kt) {
#pragma unroll
        for (int l = 0; l < 16; ++l) {
            int idx = l * 256 + t;
            int r = idx >> 6, c = idx & 63;
            xsT[c][r]  = x[(size_t)(row0 + r) * EDIM + kt * 64 + c];
            wqs[r][c]  = Wq[(size_t)(kt * 64 + r) * HDIM + c];
            wks[r][c]  = Wk[(size_t)(kt * 64 + r) * HDIM + c];
            wvs[r][c]  = Wv[(size_t)(kt * 64 + r) * HDIM + c];
        }
        __syncthreads();

#pragma unroll 2
        for (int e = 0; e < 64; ++e) {
            float wqv = wqs[e][tx];
            float wkv = wks[e][tx];
            float wvv = wvs[e][tx];
#pragma unroll
            for (int rr = 0; rr < 4; ++rr) {
                float4 xv = *(const float4*)&xsT[e][wv_ * 16 + 4 * rr];
                accq[4*rr+0] = fmaf(xv.x, wqv, accq[4*rr+0]);
                accq[4*rr+1] = fmaf(xv.y, wqv, accq[4*rr+1]);
                accq[4*rr+2] = fmaf(xv.z, wqv, accq[4*rr+2]);
                accq[4*rr+3] = fmaf(xv.w, wqv, accq[4*rr+3]);
                acck[4*rr+0] = fmaf(xv.x, wkv, acck[4*rr+0]);
                acck[4*rr+1] = fmaf(xv.y, wkv, acck[4*rr+1]);
                acck[4*rr+2] = fmaf(xv.z, wkv, acck[4*rr+2]);
                acck[4*rr+3] = fmaf(xv.w, wkv, acck[4*rr+3]);
                accv[4*rr+0] = fmaf(xv.x, wvv, accv[4*rr+0]);
                accv[4*rr+1] = fmaf(xv.y, wvv, accv[4*rr+1]);
                accv[4*rr+2] = fmaf(xv.z, wvv, accv[4*rr+2]);
                accv[4*rr+3] = fmaf(xv.w, wvv, accv[4*rr+3]);
            }
        }
        __syncthreads();
    }

    float bqv = bq[tx], bkv = bk[tx], bvv = bv[tx];
#pragma unroll
    for (int r = 0; r < 16; ++r) {
        size_t row = (size_t)(row0 + wv_ * 16 + r);
        Qb[row * HDIM + tx] = accq[r] + bqv;
        Kb[row * HDIM + tx] = acck[r] + bkv;
        Vb[row * HDIM + tx] = accv[r] + bvv;
    }
}

// ---------------------------------------------------------------------------
// Flash-style causal attention.  Grid: (T/64, B), 256 threads.
// Block handles Q rows [iq*64, iq*64+64); loops K-tiles jt = 0..iq.
// Thread (ty=t/16, tx=t%16) owns S/O rows 4*ty+i, cols tx+16*j
// (cols spaced 16 -> LDS rows spaced 16 -> bank offsets spread; only the
// free 2-way aliasing remains).  V staged transposed [d][k] so PV
// vectorizes (float4 over k).
// ---------------------------------------------------------------------------
__global__ __launch_bounds__(256) void attn_kernel(
    const float* __restrict__ Qb, const float* __restrict__ Kb,
    const float* __restrict__ Vb, float* __restrict__ out)
{
    __shared__ float Qs[64][68];
    __shared__ float Ks[64][68];
    __shared__ float VsT[64][68];    // [d][k]
    __shared__ float Ss[64][68];
    __shared__ float mrow[64], lrow[64], arow[64];

    const int t  = threadIdx.x;
    const int tx = t & 15;
    const int ty = t >> 4;
    const int iq = blockIdx.x;
    const int b  = blockIdx.y;
    const size_t base = (size_t)b * TDIM * HDIM;
    const int q0 = iq * 64;

#pragma unroll
    for (int l = 0; l < 16; ++l) {
        int idx = l * 256 + t;
        int r = idx >> 6, c = idx & 63;
        Qs[r][c] = Qb[base + (size_t)(q0 + r) * HDIM + c];
    }
    if (t < 64) { mrow[t] = -__builtin_inff(); lrow[t] = 0.f; }

    float O[4][4];
#pragma unroll
    for (int i = 0; i < 4; ++i)
#pragma unroll
        for (int j = 0; j < 4; ++j) O[i][j] = 0.f;

    for (int jt = 0; jt <= iq; ++jt) {
        __syncthreads();             // protect Ks/VsT/Ss reuse (and Qs 1st iter)
#pragma unroll
        for (int l = 0; l < 16; ++l) {
            int idx = l * 256 + t;
            int r = idx >> 6, c = idx & 63;
            float kv = Kb[base + (size_t)(jt * 64 + r) * HDIM + c];
            float vv = Vb[base + (size_t)(jt * 64 + r) * HDIM + c];
            Ks[r][c]  = kv;
            VsT[c][r] = vv;
        }
        __syncthreads();

        // ---- S = Q K^T ----
        float s[4][4];
#pragma unroll
        for (int i = 0; i < 4; ++i)
#pragma unroll
            for (int j = 0; j < 4; ++j) s[i][j] = 0.f;

#pragma unroll 4
        for (int d4 = 0; d4 < 16; ++d4) {
            float4 qv[4], kv[4];
#pragma unroll
            for (int i = 0; i < 4; ++i) qv[i] = *(const float4*)&Qs[4 * ty + i][4 * d4];
#pragma unroll
            for (int j = 0; j < 4; ++j) kv[j] = *(const float4*)&Ks[tx + 16 * j][4 * d4];
#pragma unroll
            for (int i = 0; i < 4; ++i)
#pragma unroll
                for (int j = 0; j < 4; ++j) {
                    s[i][j] = fmaf(qv[i].x, kv[j].x, s[i][j]);
                    s[i][j] = fmaf(qv[i].y, kv[j].y, s[i][j]);
                    s[i][j] = fmaf(qv[i].z, kv[j].z, s[i][j]);
                    s[i][j] = fmaf(qv[i].w, kv[j].w, s[i][j]);
                }
        }

        // ---- scale + causal mask -> Ss ----
        const float scale = 0.125f;   // 1/sqrt(64)
#pragma unroll
        for (int i = 0; i < 4; ++i) {
            int qg = q0 + 4 * ty + i;
#pragma unroll
            for (int j = 0; j < 4; ++j) {
                int kg = jt * 64 + tx + 16 * j;
                Ss[4 * ty + i][tx + 16 * j] =
                    (kg <= qg) ? s[i][j] * scale : -__builtin_inff();
            }
        }
        __syncthreads();

        // ---- online softmax, one thread per q-row ----
        if (t < 64) {
            float mold = mrow[t];
            float mnew = mold;
#pragma unroll
            for (int c4 = 0; c4 < 16; ++c4) {
                float4 v = *(const float4*)&Ss[t][4 * c4];
                mnew = fmaxf(mnew, fmaxf(fmaxf(v.x, v.y), fmaxf(v.z, v.w)));
            }
            float rsum = 0.f;
#pragma unroll
            for (int c4 = 0; c4 < 16; ++c4) {
                float4 v = *(float4*)&Ss[t][4 * c4];
                v.x = __expf(v.x - mnew);
                v.y = __expf(v.y - mnew);
                v.z = __expf(v.z - mnew);
                v.w = __expf(v.w - mnew);
                rsum += (v.x + v.y) + (v.z + v.w);
                *(float4*)&Ss[t][4 * c4] = v;
            }
            float alpha = __expf(mold - mnew);   // exp(-inf)=0 first tile
            mrow[t] = mnew;
            lrow[t] = lrow[t] * alpha + rsum;
            arow[t] = alpha;
        }
        __syncthreads();

        // ---- O = O*alpha + P @ V ----
        float al[4];
#pragma unroll
        for (int i = 0; i < 4; ++i) al[i] = arow[4 * ty + i];
#pragma unroll
        for (int i = 0; i < 4; ++i)
#pragma unroll
            for (int j = 0; j < 4; ++j) O[i][j] *= al[i];

#pragma unroll 4
        for (int k4 = 0; k4 < 16; ++k4) {
            float4 pv[4], vv[4];
#pragma unroll
            for (int i = 0; i < 4; ++i) pv[i] = *(const float4*)&Ss[4 * ty + i][4 * k4];
#pragma unroll
            for (int j = 0; j < 4; ++j) vv[j] = *(const float4*)&VsT[tx + 16 * j][4 * k4];
#pragma unroll
            for (int i = 0; i < 4; ++i)
#pragma unroll
                for (int j = 0; j < 4; ++j) {
                    O[i][j] = fmaf(pv[i].x, vv[j].x, O[i][j]);
                    O[i][j] = fmaf(pv[i].y, vv[j].y, O[i][j]);
                    O[i][j] = fmaf(pv[i].z, vv[j].z, O[i][j]);
                    O[i][j] = fmaf(pv[i].w, vv[j].w, O[i][j]);
                }
        }
    }
    __syncthreads();

    // ---- normalize + store ----
    float linv[4];
#pragma unroll
    for (int i = 0; i < 4; ++i) linv[i] = 1.f / lrow[4 * ty + i];
#pragma unroll
    for (int i = 0; i < 4; ++i) {
        size_t row = (size_t)(q0 + 4 * ty + i);
#pragma unroll
        for (int j = 0; j < 4; ++j)
            out[base + row * HDIM + tx + 16 * j] = O[i][j] * linv[i];
    }
}

extern "C" void kernel_launch(void* const* d_in, const int* in_sizes, int n_in,
                              void* d_out, int out_size, void* d_ws, size_t ws_size,
                              hipStream_t stream) {
    const float* x  = (const float*)d_in[0];
    const float* Wq = (const float*)d_in[1];
    const float* bq = (const float*)d_in[2];
    const float* Wk = (const float*)d_in[3];
    const float* bk = (const float*)d_in[4];
    const float* Wv = (const float*)d_in[5];
    const float* bv = (const float*)d_in[6];
    float* out = (float*)d_out;

    const size_t n = (size_t)BDIM * TDIM * HDIM;   // 1,048,576 elems
    float* Qb = (float*)d_ws;
    float* Kb = Qb + n;
    float* Vb = Kb + n;

    proj_kernel<<<dim3(BDIM * TDIM / 64), 256, 0, stream>>>(
        x, Wq, bq, Wk, bk, Wv, bv, Qb, Kb, Vb);
    attn_kernel<<<dim3(TDIM / 64, BDIM), 256, 0, stream>>>(Qb, Kb, Vb, out);
}

// Round 3
// 183.568 us; speedup vs baseline: 2.4071x; 2.4071x over previous
//
#include <hip/hip_runtime.h>
#include <math.h>
#include <stdint.h>

#define BDIM 8
#define TDIM 2048
#define EDIM 1024
#define HDIM 64

typedef short bf16x8 __attribute__((ext_vector_type(8)));   // 8 bf16 (4 VGPRs)
typedef float f32x4 __attribute__((ext_vector_type(4)));    // 4 fp32 acc

__device__ __forceinline__ unsigned short f2bf(float f) {   // RNE fp32->bf16
    uint32_t u = __builtin_bit_cast(uint32_t, f);
    u += 0x7fffu + ((u >> 16) & 1u);
    return (unsigned short)(u >> 16);
}

// ---------------------------------------------------------------------------
// prep_w: W[e][h] fp32 -> WT[h][e] bf16  (so proj B-frags are contiguous)
// ---------------------------------------------------------------------------
__global__ __launch_bounds__(256) void prep_w(
    const float* __restrict__ Wq, const float* __restrict__ Wk,
    const float* __restrict__ Wv,
    unsigned short* __restrict__ WqT, unsigned short* __restrict__ WkT,
    unsigned short* __restrict__ WvT)
{
    int id = blockIdx.x * 256 + threadIdx.x;   // 0..65535
    int e = id >> 6, h = id & 63;              // coalesced reads
    int oi = h * EDIM + e;
    WqT[oi] = f2bf(Wq[id]);
    WkT[oi] = f2bf(Wk[id]);
    WvT[oi] = f2bf(Wv[id]);
}

// ---------------------------------------------------------------------------
// proj: Q/K/V = x@W + b via bf16 MFMA.  Grid 256 blocks, 256 thr.
// Block: 64 rows x 64 h.  Wave w owns 16-row strip.  K-loop over e in 64s.
// A-frag: Xs[16w+ln][8*quad + 32c]  (b128).  B-frag: WsT[16j+ln][8*quad+32c].
// ---------------------------------------------------------------------------
__global__ __launch_bounds__(256) void proj_kernel(
    const float* __restrict__ x,
    const unsigned short* __restrict__ WqT, const unsigned short* __restrict__ WkT,
    const unsigned short* __restrict__ WvT,
    const float* __restrict__ bq, const float* __restrict__ bk,
    const float* __restrict__ bv,
    unsigned short* __restrict__ Qb, unsigned short* __restrict__ Kb,
    unsigned short* __restrict__ Vb)
{
    __shared__ unsigned short Xs[64][72];    // pad 8 bf16 -> row stride 144B (16B-mult)
    __shared__ unsigned short Wqs[64][72];
    __shared__ unsigned short Wks[64][72];
    __shared__ unsigned short Wvs[64][72];

    const int t = threadIdx.x;
    const int lane = t & 63, w = t >> 6, quad = lane >> 4, ln = lane & 15;
    const int row0 = blockIdx.x * 64;
    const int sr = t >> 2;              // staging row 0..63
    const int sc = (t & 3) << 4;        // staging col 0,16,32,48

    f32x4 accq[4], acck[4], accv[4];
#pragma unroll
    for (int j = 0; j < 4; ++j) {
        accq[j] = (f32x4)(0.f); acck[j] = (f32x4)(0.f); accv[j] = (f32x4)(0.f);
    }

    for (int kt = 0; kt < EDIM / 64; ++kt) {
        __syncthreads();
        // ---- stage x (fp32 -> bf16) ----
        const float* xp = &x[(size_t)(row0 + sr) * EDIM + kt * 64 + sc];
        float4 x0 = *(const float4*)(xp);
        float4 x1 = *(const float4*)(xp + 4);
        float4 x2 = *(const float4*)(xp + 8);
        float4 x3 = *(const float4*)(xp + 12);
        bf16x8 xb0, xb1;
        xb0[0]=(short)f2bf(x0.x); xb0[1]=(short)f2bf(x0.y); xb0[2]=(short)f2bf(x0.z); xb0[3]=(short)f2bf(x0.w);
        xb0[4]=(short)f2bf(x1.x); xb0[5]=(short)f2bf(x1.y); xb0[6]=(short)f2bf(x1.z); xb0[7]=(short)f2bf(x1.w);
        xb1[0]=(short)f2bf(x2.x); xb1[1]=(short)f2bf(x2.y); xb1[2]=(short)f2bf(x2.z); xb1[3]=(short)f2bf(x2.w);
        xb1[4]=(short)f2bf(x3.x); xb1[5]=(short)f2bf(x3.y); xb1[6]=(short)f2bf(x3.z); xb1[7]=(short)f2bf(x3.w);
        *(bf16x8*)&Xs[sr][sc]     = xb0;
        *(bf16x8*)&Xs[sr][sc + 8] = xb1;
        // ---- stage W tiles (already bf16, transposed [h][e]) ----
        size_t wo = (size_t)sr * EDIM + kt * 64 + sc;
        *(bf16x8*)&Wqs[sr][sc]     = *(const bf16x8*)&WqT[wo];
        *(bf16x8*)&Wqs[sr][sc + 8] = *(const bf16x8*)&WqT[wo + 8];
        *(bf16x8*)&Wks[sr][sc]     = *(const bf16x8*)&WkT[wo];
        *(bf16x8*)&Wks[sr][sc + 8] = *(const bf16x8*)&WkT[wo + 8];
        *(bf16x8*)&Wvs[sr][sc]     = *(const bf16x8*)&WvT[wo];
        *(bf16x8*)&Wvs[sr][sc + 8] = *(const bf16x8*)&WvT[wo + 8];
        __syncthreads();

        bf16x8 xa0 = *(const bf16x8*)&Xs[16 * w + ln][8 * quad];
        bf16x8 xa1 = *(const bf16x8*)&Xs[16 * w + ln][32 + 8 * quad];
#pragma unroll
        for (int j = 0; j < 4; ++j) {
            bf16x8 w0, w1;
            w0 = *(const bf16x8*)&Wqs[16 * j + ln][8 * quad];
            w1 = *(const bf16x8*)&Wqs[16 * j + ln][32 + 8 * quad];
            accq[j] = __builtin_amdgcn_mfma_f32_16x16x32_bf16(xa0, w0, accq[j], 0, 0, 0);
            accq[j] = __builtin_amdgcn_mfma_f32_16x16x32_bf16(xa1, w1, accq[j], 0, 0, 0);
            w0 = *(const bf16x8*)&Wks[16 * j + ln][8 * quad];
            w1 = *(const bf16x8*)&Wks[16 * j + ln][32 + 8 * quad];
            acck[j] = __builtin_amdgcn_mfma_f32_16x16x32_bf16(xa0, w0, acck[j], 0, 0, 0);
            acck[j] = __builtin_amdgcn_mfma_f32_16x16x32_bf16(xa1, w1, acck[j], 0, 0, 0);
            w0 = *(const bf16x8*)&Wvs[16 * j + ln][8 * quad];
            w1 = *(const bf16x8*)&Wvs[16 * j + ln][32 + 8 * quad];
            accv[j] = __builtin_amdgcn_mfma_f32_16x16x32_bf16(xa0, w0, accv[j], 0, 0, 0);
            accv[j] = __builtin_amdgcn_mfma_f32_16x16x32_bf16(xa1, w1, accv[j], 0, 0, 0);
        }
    }

    // ---- epilogue: bias + bf16 store (C/D layout: row=4*quad+reg, col=ln+16j)
#pragma unroll
    for (int j = 0; j < 4; ++j) {
        int col = 16 * j + ln;
        float bqv = bq[col], bkv = bk[col], bvv = bv[col];
#pragma unroll
        for (int r = 0; r < 4; ++r) {
            size_t row = (size_t)(row0 + 16 * w + 4 * quad + r);
            Qb[row * HDIM + col] = f2bf(accq[j][r] + bqv);
            Kb[row * HDIM + col] = f2bf(acck[j][r] + bkv);
            Vb[row * HDIM + col] = f2bf(accv[j][r] + bvv);
        }
    }
}

// ---------------------------------------------------------------------------
// Flash causal attention, bf16 MFMA.  Grid (32, 8), 256 thr.
// Wave w owns Q strip rows [16w,16w+16) of the 64-row block tile; softmax
// state (m,l) lives in registers, row-reduction within a 16-lane quad via
// __shfl_xor.  Q A-frags loaded from global once.  K row-major LDS; V
// transposed LDS; P round-trips through per-wave-private LDS strip.
// ---------------------------------------------------------------------------
__global__ __launch_bounds__(256) void attn_kernel(
    const unsigned short* __restrict__ Qb, const unsigned short* __restrict__ Kb,
    const unsigned short* __restrict__ Vb, float* __restrict__ out)
{
    __shared__ unsigned short Ks[64][72];
    __shared__ unsigned short VsT[64][72];   // [d][k]
    __shared__ unsigned short Ps[64][72];    // [q][k] bf16

    const int t = threadIdx.x;
    const int lane = t & 63, w = t >> 6, quad = lane >> 4, ln = lane & 15;
    const int iq = blockIdx.x;
    const int b  = blockIdx.y;
    const int q0 = iq * 64;
    const size_t base = (size_t)b * TDIM * HDIM;
    const int sr = t >> 2;
    const int sc = (t & 3) << 4;

    // Q A-frags (persistent): rows 16w+ln, k-chunks 8*quad (+32)
    const size_t qrow = base + (size_t)(q0 + 16 * w + ln) * HDIM;
    bf16x8 qa0 = *(const bf16x8*)&Qb[qrow + 8 * quad];
    bf16x8 qa1 = *(const bf16x8*)&Qb[qrow + 32 + 8 * quad];

    f32x4 od[4];
#pragma unroll
    for (int j = 0; j < 4; ++j) od[j] = (f32x4)(0.f);
    float mrow[4], lrow[4];
#pragma unroll
    for (int r = 0; r < 4; ++r) { mrow[r] = -INFINITY; lrow[r] = 0.f; }

    const float scale = 0.125f;   // 1/sqrt(64)

    for (int jt = 0; jt <= iq; ++jt) {
        __syncthreads();   // protect Ks/VsT from previous iteration's readers
        // ---- stage K (row-major) and V (transposed) ----
        {
            size_t ko = base + (size_t)(jt * 64 + sr) * HDIM + sc;
            *(bf16x8*)&Ks[sr][sc]     = *(const bf16x8*)&Kb[ko];
            *(bf16x8*)&Ks[sr][sc + 8] = *(const bf16x8*)&Kb[ko + 8];
            bf16x8 v0 = *(const bf16x8*)&Vb[ko];
            bf16x8 v1 = *(const bf16x8*)&Vb[ko + 8];
#pragma unroll
            for (int i = 0; i < 8; ++i) {
                VsT[sc + i][sr]     = (unsigned short)v0[i];
                VsT[sc + 8 + i][sr] = (unsigned short)v1[i];
            }
        }
        __syncthreads();

        // ---- S = Q K^T (4 n-tiles x 2 k-chunks) ----
        f32x4 s[4];
#pragma unroll
        for (int j = 0; j < 4; ++j) {
            bf16x8 kb0 = *(const bf16x8*)&Ks[16 * j + ln][8 * quad];
            bf16x8 kb1 = *(const bf16x8*)&Ks[16 * j + ln][32 + 8 * quad];
            s[j] = (f32x4)(0.f);
            s[j] = __builtin_amdgcn_mfma_f32_16x16x32_bf16(qa0, kb0, s[j], 0, 0, 0);
            s[j] = __builtin_amdgcn_mfma_f32_16x16x32_bf16(qa1, kb1, s[j], 0, 0, 0);
        }

        // ---- scale + causal mask (diagonal tile only; uniform branch) ----
        if (jt == iq) {
#pragma unroll
            for (int j = 0; j < 4; ++j) {
                int kg = jt * 64 + 16 * j + ln;
#pragma unroll
                for (int r = 0; r < 4; ++r) {
                    int qg = q0 + 16 * w + 4 * quad + r;
                    s[j][r] = (kg <= qg) ? s[j][r] * scale : -INFINITY;
                }
            }
        } else {
#pragma unroll
            for (int j = 0; j < 4; ++j)
#pragma unroll
                for (int r = 0; r < 4; ++r) s[j][r] *= scale;
        }

        // ---- online softmax (per row r; reduce across 16-lane quad) ----
        float mx[4];
#pragma unroll
        for (int r = 0; r < 4; ++r)
            mx[r] = fmaxf(fmaxf(s[0][r], s[1][r]), fmaxf(s[2][r], s[3][r]));
#pragma unroll
        for (int d = 1; d < 16; d <<= 1)
#pragma unroll
            for (int r = 0; r < 4; ++r)
                mx[r] = fmaxf(mx[r], __shfl_xor(mx[r], d));

        float al[4], rs[4];
#pragma unroll
        for (int r = 0; r < 4; ++r) {
            float mn = fmaxf(mrow[r], mx[r]);
            al[r] = __expf(mrow[r] - mn);    // 0 on first tile (mold=-inf)
            mrow[r] = mn;
            float p0 = __expf(s[0][r] - mn);
            float p1 = __expf(s[1][r] - mn);
            float p2 = __expf(s[2][r] - mn);
            float p3 = __expf(s[3][r] - mn);
            s[0][r] = p0; s[1][r] = p1; s[2][r] = p2; s[3][r] = p3;
            rs[r] = (p0 + p1) + (p2 + p3);
        }
#pragma unroll
        for (int d = 1; d < 16; d <<= 1)
#pragma unroll
            for (int r = 0; r < 4; ++r)
                rs[r] += __shfl_xor(rs[r], d);
#pragma unroll
        for (int r = 0; r < 4; ++r) lrow[r] = lrow[r] * al[r] + rs[r];

        // ---- rescale O, P -> LDS (own 16-row strip: no block sync needed) --
#pragma unroll
        for (int j = 0; j < 4; ++j)
#pragma unroll
            for (int r = 0; r < 4; ++r) {
                od[j][r] *= al[r];
                Ps[16 * w + 4 * quad + r][16 * j + ln] = f2bf(s[j][r]);
            }

        // ---- O += P V ----
        bf16x8 pa0 = *(const bf16x8*)&Ps[16 * w + ln][8 * quad];
        bf16x8 pa1 = *(const bf16x8*)&Ps[16 * w + ln][32 + 8 * quad];
#pragma unroll
        for (int j = 0; j < 4; ++j) {
            bf16x8 vb0 = *(const bf16x8*)&VsT[16 * j + ln][8 * quad];
            bf16x8 vb1 = *(const bf16x8*)&VsT[16 * j + ln][32 + 8 * quad];
            od[j] = __builtin_amdgcn_mfma_f32_16x16x32_bf16(pa0, vb0, od[j], 0, 0, 0);
            od[j] = __builtin_amdgcn_mfma_f32_16x16x32_bf16(pa1, vb1, od[j], 0, 0, 0);
        }
    }

    // ---- normalize + fp32 store ----
    float linv[4];
#pragma unroll
    for (int r = 0; r < 4; ++r) linv[r] = 1.f / lrow[r];
#pragma unroll
    for (int j = 0; j < 4; ++j)
#pragma unroll
        for (int r = 0; r < 4; ++r) {
            size_t row = (size_t)(q0 + 16 * w + 4 * quad + r);
            out[base + row * HDIM + 16 * j + ln] = od[j][r] * linv[r];
        }
}

extern "C" void kernel_launch(void* const* d_in, const int* in_sizes, int n_in,
                              void* d_out, int out_size, void* d_ws, size_t ws_size,
                              hipStream_t stream) {
    const float* x  = (const float*)d_in[0];
    const float* Wq = (const float*)d_in[1];
    const float* bq = (const float*)d_in[2];
    const float* Wk = (const float*)d_in[3];
    const float* bk = (const float*)d_in[4];
    const float* Wv = (const float*)d_in[5];
    const float* bv = (const float*)d_in[6];
    float* out = (float*)d_out;

    const size_t n = (size_t)BDIM * TDIM * HDIM;     // 1,048,576
    unsigned short* Qb  = (unsigned short*)d_ws;
    unsigned short* Kb  = Qb + n;
    unsigned short* Vb  = Kb + n;
    unsigned short* WqT = Vb + n;                    // 64K elems each
    unsigned short* WkT = WqT + (size_t)EDIM * HDIM;
    unsigned short* WvT = WkT + (size_t)EDIM * HDIM;

    prep_w<<<dim3(EDIM * HDIM / 256), 256, 0, stream>>>(Wq, Wk, Wv, WqT, WkT, WvT);
    proj_kernel<<<dim3(BDIM * TDIM / 64), 256, 0, stream>>>(
        x, WqT, WkT, WvT, bq, bk, bv, Qb, Kb, Vb);
    attn_kernel<<<dim3(TDIM / 64, BDIM), 256, 0, stream>>>(Qb, Kb, Vb, out);
}

// Round 4
// 156.571 us; speedup vs baseline: 2.8222x; 1.1724x over previous
//
#include <hip/hip_runtime.h>
#include <math.h>
#include <stdint.h>

#define BDIM 8
#define TDIM 2048
#define EDIM 1024
#define HDIM 64
#define NCHUNK 144   // sum over iq of ceil((iq+1)/4), iq in [0,32)

typedef short bf16x8 __attribute__((ext_vector_type(8)));   // 8 bf16 (4 VGPRs)
typedef float f32x4 __attribute__((ext_vector_type(4)));    // 4 fp32 acc

__device__ __forceinline__ unsigned short f2bf(float f) {   // RNE fp32->bf16
    uint32_t u = __builtin_bit_cast(uint32_t, f);
    u += 0x7fffu + ((u >> 16) & 1u);
    return (unsigned short)(u >> 16);
}

// ---------------------------------------------------------------------------
// prep_w: W[e][h] fp32 -> WT[h][e] bf16  (so proj B-frags are contiguous)
// ---------------------------------------------------------------------------
__global__ __launch_bounds__(256) void prep_w(
    const float* __restrict__ Wq, const float* __restrict__ Wk,
    const float* __restrict__ Wv,
    unsigned short* __restrict__ WqT, unsigned short* __restrict__ WkT,
    unsigned short* __restrict__ WvT)
{
    int id = blockIdx.x * 256 + threadIdx.x;   // 0..65535
    int e = id >> 6, h = id & 63;              // coalesced reads
    int oi = h * EDIM + e;
    WqT[oi] = f2bf(Wq[id]);
    WkT[oi] = f2bf(Wk[id]);
    WvT[oi] = f2bf(Wv[id]);
}

// ---------------------------------------------------------------------------
// proj: Q/K/V = x@W + b via bf16 MFMA.  Grid 256 blocks, 256 thr.
// Q,K stored row-major [b*T][h]; V stored TRANSPOSED [b][d][T] so the attn
// kernel can stage V^T with vector loads (no LDS transpose).
// ---------------------------------------------------------------------------
__global__ __launch_bounds__(256) void proj_kernel(
    const float* __restrict__ x,
    const unsigned short* __restrict__ WqT, const unsigned short* __restrict__ WkT,
    const unsigned short* __restrict__ WvT,
    const float* __restrict__ bq, const float* __restrict__ bk,
    const float* __restrict__ bv,
    unsigned short* __restrict__ Qb, unsigned short* __restrict__ Kb,
    unsigned short* __restrict__ VbT)
{
    __shared__ unsigned short Xs[64][72];
    __shared__ unsigned short Wqs[64][72];
    __shared__ unsigned short Wks[64][72];
    __shared__ unsigned short Wvs[64][72];

    const int t = threadIdx.x;
    const int lane = t & 63, w = t >> 6, quad = lane >> 4, ln = lane & 15;
    const int row0 = blockIdx.x * 64;
    const int sr = t >> 2;              // staging row 0..63
    const int sc = (t & 3) << 4;        // staging col 0,16,32,48

    f32x4 accq[4], acck[4], accv[4];
#pragma unroll
    for (int j = 0; j < 4; ++j) {
        accq[j] = (f32x4)(0.f); acck[j] = (f32x4)(0.f); accv[j] = (f32x4)(0.f);
    }

    for (int kt = 0; kt < EDIM / 64; ++kt) {
        __syncthreads();
        const float* xp = &x[(size_t)(row0 + sr) * EDIM + kt * 64 + sc];
        float4 x0 = *(const float4*)(xp);
        float4 x1 = *(const float4*)(xp + 4);
        float4 x2 = *(const float4*)(xp + 8);
        float4 x3 = *(const float4*)(xp + 12);
        bf16x8 xb0, xb1;
        xb0[0]=(short)f2bf(x0.x); xb0[1]=(short)f2bf(x0.y); xb0[2]=(short)f2bf(x0.z); xb0[3]=(short)f2bf(x0.w);
        xb0[4]=(short)f2bf(x1.x); xb0[5]=(short)f2bf(x1.y); xb0[6]=(short)f2bf(x1.z); xb0[7]=(short)f2bf(x1.w);
        xb1[0]=(short)f2bf(x2.x); xb1[1]=(short)f2bf(x2.y); xb1[2]=(short)f2bf(x2.z); xb1[3]=(short)f2bf(x2.w);
        xb1[4]=(short)f2bf(x3.x); xb1[5]=(short)f2bf(x3.y); xb1[6]=(short)f2bf(x3.z); xb1[7]=(short)f2bf(x3.w);
        *(bf16x8*)&Xs[sr][sc]     = xb0;
        *(bf16x8*)&Xs[sr][sc + 8] = xb1;
        size_t wo = (size_t)sr * EDIM + kt * 64 + sc;
        *(bf16x8*)&Wqs[sr][sc]     = *(const bf16x8*)&WqT[wo];
        *(bf16x8*)&Wqs[sr][sc + 8] = *(const bf16x8*)&WqT[wo + 8];
        *(bf16x8*)&Wks[sr][sc]     = *(const bf16x8*)&WkT[wo];
        *(bf16x8*)&Wks[sr][sc + 8] = *(const bf16x8*)&WkT[wo + 8];
        *(bf16x8*)&Wvs[sr][sc]     = *(const bf16x8*)&WvT[wo];
        *(bf16x8*)&Wvs[sr][sc + 8] = *(const bf16x8*)&WvT[wo + 8];
        __syncthreads();

        bf16x8 xa0 = *(const bf16x8*)&Xs[16 * w + ln][8 * quad];
        bf16x8 xa1 = *(const bf16x8*)&Xs[16 * w + ln][32 + 8 * quad];
#pragma unroll
        for (int j = 0; j < 4; ++j) {
            bf16x8 w0, w1;
            w0 = *(const bf16x8*)&Wqs[16 * j + ln][8 * quad];
            w1 = *(const bf16x8*)&Wqs[16 * j + ln][32 + 8 * quad];
            accq[j] = __builtin_amdgcn_mfma_f32_16x16x32_bf16(xa0, w0, accq[j], 0, 0, 0);
            accq[j] = __builtin_amdgcn_mfma_f32_16x16x32_bf16(xa1, w1, accq[j], 0, 0, 0);
            w0 = *(const bf16x8*)&Wks[16 * j + ln][8 * quad];
            w1 = *(const bf16x8*)&Wks[16 * j + ln][32 + 8 * quad];
            acck[j] = __builtin_amdgcn_mfma_f32_16x16x32_bf16(xa0, w0, acck[j], 0, 0, 0);
            acck[j] = __builtin_amdgcn_mfma_f32_16x16x32_bf16(xa1, w1, acck[j], 0, 0, 0);
            w0 = *(const bf16x8*)&Wvs[16 * j + ln][8 * quad];
            w1 = *(const bf16x8*)&Wvs[16 * j + ln][32 + 8 * quad];
            accv[j] = __builtin_amdgcn_mfma_f32_16x16x32_bf16(xa0, w0, accv[j], 0, 0, 0);
            accv[j] = __builtin_amdgcn_mfma_f32_16x16x32_bf16(xa1, w1, accv[j], 0, 0, 0);
        }
    }

    // epilogue: bias + bf16 store (C/D layout: row=4*quad+reg, col=ln+16j)
#pragma unroll
    for (int j = 0; j < 4; ++j) {
        int col = 16 * j + ln;
        float bqv = bq[col], bkv = bk[col], bvv = bv[col];
#pragma unroll
        for (int r = 0; r < 4; ++r) {
            size_t row = (size_t)(row0 + 16 * w + 4 * quad + r);
            Qb[row * HDIM + col] = f2bf(accq[j][r] + bqv);
            Kb[row * HDIM + col] = f2bf(acck[j][r] + bkv);
            int bb = (int)(row >> 11);            // row / TDIM
            int tr = (int)(row & 2047);           // row % TDIM
            VbT[((size_t)bb * HDIM + col) * TDIM + tr] = f2bf(accv[j][r] + bvv);
        }
    }
}

// ---------------------------------------------------------------------------
// Split-K flash partial.  Grid (NCHUNK=144, B).  Each block = one
// (q-tile iq, K-chunk of 4 tiles) pair -> perfectly balanced work.
// Writes unnormalized O (fp32 64x64), m, l per q-row.
// Chunk flattening: group g = iq>>2 has (g+1) chunks per q-tile,
// group offset 2g(g+1).
// ---------------------------------------------------------------------------
__global__ __launch_bounds__(256) void attn_partial(
    const unsigned short* __restrict__ Qb, const unsigned short* __restrict__ Kb,
    const unsigned short* __restrict__ VbT,
    float* __restrict__ PO, float* __restrict__ Pm, float* __restrict__ Pl)
{
    __shared__ unsigned short Ks[64][72];
    __shared__ unsigned short VsT[64][72];   // [d][k]
    __shared__ unsigned short Ps[64][72];    // [q][k] bf16

    const int t = threadIdx.x;
    const int lane = t & 63, w = t >> 6, quad = lane >> 4, ln = lane & 15;
    const int f = blockIdx.x;
    const int b = blockIdx.y;

    // decode (iq, chunk) from f
    int g = 0;
    while (f >= 2 * (g + 1) * (g + 2)) ++g;       // g in 0..7
    const int r_  = f - 2 * g * (g + 1);
    const int iq  = 4 * g + r_ / (g + 1);
    const int ch  = r_ % (g + 1);

    const int q0 = iq * 64;
    const size_t base = (size_t)b * TDIM * HDIM;
    const int sr = t >> 2;
    const int sc = (t & 3) << 4;

    const size_t qrow = base + (size_t)(q0 + 16 * w + ln) * HDIM;
    bf16x8 qa0 = *(const bf16x8*)&Qb[qrow + 8 * quad];
    bf16x8 qa1 = *(const bf16x8*)&Qb[qrow + 32 + 8 * quad];

    f32x4 od[4];
#pragma unroll
    for (int j = 0; j < 4; ++j) od[j] = (f32x4)(0.f);
    float mrow[4], lrow[4];
#pragma unroll
    for (int r = 0; r < 4; ++r) { mrow[r] = -INFINITY; lrow[r] = 0.f; }

    const float scale = 0.125f;   // 1/sqrt(64)
    int j1 = 4 * ch + 3; if (j1 > iq) j1 = iq;

    for (int jt = 4 * ch; jt <= j1; ++jt) {
        __syncthreads();
        {
            size_t ko = base + (size_t)(jt * 64 + sr) * HDIM + sc;
            *(bf16x8*)&Ks[sr][sc]     = *(const bf16x8*)&Kb[ko];
            *(bf16x8*)&Ks[sr][sc + 8] = *(const bf16x8*)&Kb[ko + 8];
            const unsigned short* vrow =
                &VbT[((size_t)b * HDIM + sr) * TDIM + jt * 64 + sc];
            *(bf16x8*)&VsT[sr][sc]     = *(const bf16x8*)vrow;
            *(bf16x8*)&VsT[sr][sc + 8] = *(const bf16x8*)(vrow + 8);
        }
        __syncthreads();

        // ---- S = Q K^T ----
        f32x4 s[4];
#pragma unroll
        for (int j = 0; j < 4; ++j) {
            bf16x8 kb0 = *(const bf16x8*)&Ks[16 * j + ln][8 * quad];
            bf16x8 kb1 = *(const bf16x8*)&Ks[16 * j + ln][32 + 8 * quad];
            s[j] = (f32x4)(0.f);
            s[j] = __builtin_amdgcn_mfma_f32_16x16x32_bf16(qa0, kb0, s[j], 0, 0, 0);
            s[j] = __builtin_amdgcn_mfma_f32_16x16x32_bf16(qa1, kb1, s[j], 0, 0, 0);
        }

        // ---- scale + causal mask (diagonal tile only) ----
        if (jt == iq) {
#pragma unroll
            for (int j = 0; j < 4; ++j) {
                int kg = jt * 64 + 16 * j + ln;
#pragma unroll
                for (int r = 0; r < 4; ++r) {
                    int qg = q0 + 16 * w + 4 * quad + r;
                    s[j][r] = (kg <= qg) ? s[j][r] * scale : -INFINITY;
                }
            }
        } else {
#pragma unroll
            for (int j = 0; j < 4; ++j)
#pragma unroll
                for (int r = 0; r < 4; ++r) s[j][r] *= scale;
        }

        // ---- online softmax (reduce across 16-lane quad) ----
        float mx[4];
#pragma unroll
        for (int r = 0; r < 4; ++r)
            mx[r] = fmaxf(fmaxf(s[0][r], s[1][r]), fmaxf(s[2][r], s[3][r]));
#pragma unroll
        for (int d = 1; d < 16; d <<= 1)
#pragma unroll
            for (int r = 0; r < 4; ++r)
                mx[r] = fmaxf(mx[r], __shfl_xor(mx[r], d));

        float al[4], rs[4];
#pragma unroll
        for (int r = 0; r < 4; ++r) {
            float mn = fmaxf(mrow[r], mx[r]);
            al[r] = __expf(mrow[r] - mn);
            mrow[r] = mn;
            float p0 = __expf(s[0][r] - mn);
            float p1 = __expf(s[1][r] - mn);
            float p2 = __expf(s[2][r] - mn);
            float p3 = __expf(s[3][r] - mn);
            s[0][r] = p0; s[1][r] = p1; s[2][r] = p2; s[3][r] = p3;
            rs[r] = (p0 + p1) + (p2 + p3);
        }
#pragma unroll
        for (int d = 1; d < 16; d <<= 1)
#pragma unroll
            for (int r = 0; r < 4; ++r)
                rs[r] += __shfl_xor(rs[r], d);
#pragma unroll
        for (int r = 0; r < 4; ++r) lrow[r] = lrow[r] * al[r] + rs[r];

        // ---- rescale O, P -> LDS (wave-private strip) ----
#pragma unroll
        for (int j = 0; j < 4; ++j)
#pragma unroll
            for (int r = 0; r < 4; ++r) {
                od[j][r] *= al[r];
                Ps[16 * w + 4 * quad + r][16 * j + ln] = f2bf(s[j][r]);
            }

        // ---- O += P V ----
        bf16x8 pa0 = *(const bf16x8*)&Ps[16 * w + ln][8 * quad];
        bf16x8 pa1 = *(const bf16x8*)&Ps[16 * w + ln][32 + 8 * quad];
#pragma unroll
        for (int j = 0; j < 4; ++j) {
            bf16x8 vb0 = *(const bf16x8*)&VsT[16 * j + ln][8 * quad];
            bf16x8 vb1 = *(const bf16x8*)&VsT[16 * j + ln][32 + 8 * quad];
            od[j] = __builtin_amdgcn_mfma_f32_16x16x32_bf16(pa0, vb0, od[j], 0, 0, 0);
            od[j] = __builtin_amdgcn_mfma_f32_16x16x32_bf16(pa1, vb1, od[j], 0, 0, 0);
        }
    }

    // ---- write partial (unnormalized O, m, l) ----
    const size_t p = (size_t)b * NCHUNK + f;
#pragma unroll
    for (int j = 0; j < 4; ++j)
#pragma unroll
        for (int r = 0; r < 4; ++r)
            PO[p * 4096 + (size_t)(16 * w + 4 * quad + r) * 64 + 16 * j + ln] = od[j][r];
    if (ln == 0) {
#pragma unroll
        for (int r = 0; r < 4; ++r) {
            Pm[p * 64 + 16 * w + 4 * quad + r] = mrow[r];
            Pl[p * 64 + 16 * w + 4 * quad + r] = lrow[r];
        }
    }
}

// ---------------------------------------------------------------------------
// Combine partials.  Grid (T/64, B), 256 thr.  Thread t: row=t>>2,
// cols (t&3)*16..+15.  nchunks = (iq>>2)+1 <= 8.
// ---------------------------------------------------------------------------
__global__ __launch_bounds__(256) void attn_combine(
    const float* __restrict__ PO, const float* __restrict__ Pm,
    const float* __restrict__ Pl, float* __restrict__ out)
{
    const int iq = blockIdx.x, b = blockIdx.y;
    const int g = iq >> 2;
    const int nch = g + 1;
    const int fbase = 2 * g * (g + 1) + (iq - 4 * g) * (g + 1);
    const int t = threadIdx.x;
    const int row = t >> 2;
    const int c0 = (t & 3) << 4;
    const size_t pbase = (size_t)b * NCHUNK + fbase;

    float M = -INFINITY;
    for (int c = 0; c < nch; ++c)
        M = fmaxf(M, Pm[(pbase + c) * 64 + row]);

    float4 a0 = {0,0,0,0}, a1 = {0,0,0,0}, a2 = {0,0,0,0}, a3 = {0,0,0,0};
    float L = 0.f;
    for (int c = 0; c < nch; ++c) {
        size_t p = pbase + c;
        float sc = __expf(Pm[p * 64 + row] - M);
        L += sc * Pl[p * 64 + row];
        const float* po = &PO[p * 4096 + (size_t)row * 64 + c0];
        float4 v0 = *(const float4*)(po);
        float4 v1 = *(const float4*)(po + 4);
        float4 v2 = *(const float4*)(po + 8);
        float4 v3 = *(const float4*)(po + 12);
        a0.x += sc*v0.x; a0.y += sc*v0.y; a0.z += sc*v0.z; a0.w += sc*v0.w;
        a1.x += sc*v1.x; a1.y += sc*v1.y; a1.z += sc*v1.z; a1.w += sc*v1.w;
        a2.x += sc*v2.x; a2.y += sc*v2.y; a2.z += sc*v2.z; a2.w += sc*v2.w;
        a3.x += sc*v3.x; a3.y += sc*v3.y; a3.z += sc*v3.z; a3.w += sc*v3.w;
    }
    float li = 1.f / L;
    a0.x*=li; a0.y*=li; a0.z*=li; a0.w*=li;
    a1.x*=li; a1.y*=li; a1.z*=li; a1.w*=li;
    a2.x*=li; a2.y*=li; a2.z*=li; a2.w*=li;
    a3.x*=li; a3.y*=li; a3.z*=li; a3.w*=li;
    float* op = &out[((size_t)b * TDIM + (size_t)iq * 64 + row) * HDIM + c0];
    *(float4*)(op)      = a0;
    *(float4*)(op + 4)  = a1;
    *(float4*)(op + 8)  = a2;
    *(float4*)(op + 12) = a3;
}

extern "C" void kernel_launch(void* const* d_in, const int* in_sizes, int n_in,
                              void* d_out, int out_size, void* d_ws, size_t ws_size,
                              hipStream_t stream) {
    const float* x  = (const float*)d_in[0];
    const float* Wq = (const float*)d_in[1];
    const float* bq = (const float*)d_in[2];
    const float* Wk = (const float*)d_in[3];
    const float* bk = (const float*)d_in[4];
    const float* Wv = (const float*)d_in[5];
    const float* bv = (const float*)d_in[6];
    float* out = (float*)d_out;

    const size_t n = (size_t)BDIM * TDIM * HDIM;     // 1,048,576
    unsigned short* Qb  = (unsigned short*)d_ws;
    unsigned short* Kb  = Qb + n;
    unsigned short* VbT = Kb + n;
    unsigned short* WqT = VbT + n;
    unsigned short* WkT = WqT + (size_t)EDIM * HDIM;
    unsigned short* WvT = WkT + (size_t)EDIM * HDIM;
    float* PO = (float*)(WvT + (size_t)EDIM * HDIM);           // 1152*4096 f32
    float* Pm = PO + (size_t)BDIM * NCHUNK * 4096;             // 1152*64
    float* Pl = Pm + (size_t)BDIM * NCHUNK * 64;

    prep_w<<<dim3(EDIM * HDIM / 256), 256, 0, stream>>>(Wq, Wk, Wv, WqT, WkT, WvT);
    proj_kernel<<<dim3(BDIM * TDIM / 64), 256, 0, stream>>>(
        x, WqT, WkT, WvT, bq, bk, bv, Qb, Kb, VbT);
    attn_partial<<<dim3(NCHUNK, BDIM), 256, 0, stream>>>(Qb, Kb, VbT, PO, Pm, Pl);
    attn_combine<<<dim3(TDIM / 64, BDIM), 256, 0, stream>>>(PO, Pm, Pl, out);
}